// Round 5
// baseline (476.055 us; speedup 1.0000x reference)
//
#include <hip/hip_runtime.h>
#include <hip/hip_bf16.h>
#include <math.h>

// Problem constants
#define T_TOKENS 16384
#define HID      2048
#define NE       64     // experts
#define TOPK     8
// Tiling: thread tile 4 tok x 4 exp, 128-thr block, TM=32 -> grid 512 (2 blk/CU)
#define TM       32     // tokens per block
#define BK       64     // k-chunk
#define ASTR     68     // A f32 row stride: 272 B, 16B-aligned; 4-row step = 64 B
                        //   -> the 4 broadcast A-read addrs hit distinct bank-quads
#define BSTR     68     // B' (K-major) f32 row stride: 272 B, 16B-aligned

__global__ __launch_bounds__(128) void router_kernel(
    const float* __restrict__ hidden,   // [T_TOKENS, HID]
    const float* __restrict__ weight,   // [NE, HID]
    float* __restrict__ out_logits,     // [T_TOKENS, NE]
    float* __restrict__ out_vals,       // [T_TOKENS, TOPK]
    float* __restrict__ out_idxf)       // [T_TOKENS, TOPK] (indices stored as float)
{
    // aS: [TM][ASTR] f32 row-major (token rows)      =  8704 B
    // bS: [BK][BSTR] f32 K-major (row = one k)       = 17408 B   total 26112 B
    // Epilogue aliases lg[TM][65] f64 (16640 B) over the front.
    __shared__ __align__(16) char smem[TM * ASTR * 4 + BK * BSTR * 4];
    float (*aS)[ASTR] = reinterpret_cast<float(*)[ASTR]>(smem);
    float (*bS)[BSTR] = reinterpret_cast<float(*)[BSTR]>(smem + TM * ASTR * 4);
    double (*lg)[65]  = reinterpret_cast<double(*)[65]>(smem);

    const int tid  = threadIdx.x;
    const int tok0 = blockIdx.x * TM;

    // Compute map: ty = token group (4 tokens), tx = expert group (4 experts).
    // Wave = 4 token groups x 16 expert threads:
    //   A reads: 4 distinct addrs (broadcast x16), bank-quads spread by ASTR=68.
    //   B reads: 16 lanes x contiguous 16 B = 256 B run, broadcast across groups.
    const int ty = tid >> 4;   // 0..7
    const int tx = tid & 15;   // 0..15

    // f64 accumulation (exact ranking vs numpy ref; f32 seq error flips top-8
    // ranks). f32 in LDS + inline cvt: 0.5 cvt per fma, stays under LDS roof.
    double acc[4][4];
    #pragma unroll
    for (int i = 0; i < 4; ++i)
        #pragma unroll
        for (int j = 0; j < 4; ++j) acc[i][j] = 0.0;

    // Staging maps
    const int ar = tid >> 2;           // 0..31  A row (token)
    const int ac = (tid & 3) << 4;     // 0,16,32,48  A col start (16 f32/thread)
    const int be = tid >> 1;           // 0..63  B expert row
    const int bk = (tid & 1) << 5;     // 0,32   B col start (32 f32/thread)

    for (int k0 = 0; k0 < HID; k0 += BK) {
        // ---- stage A tile [TM][BK] f32 row-major: 4 b128 writes/thread ----
        #pragma unroll
        for (int q = 0; q < 4; ++q) {
            *(float4*)&aS[ar][ac + 4 * q] =
                *(const float4*)&hidden[(size_t)(tok0 + ar) * HID + k0 + ac + 4 * q];
        }
        // ---- stage B tile [NE][BK] f32 K-major (transpose in-flight) ----
        // Write pattern per instr: bank = (4j + e) mod 32, e=0..31 distinct,
        // kc 0/32 collide 2-way only (free).
        #pragma unroll
        for (int q = 0; q < 8; ++q) {
            const float4 w = *(const float4*)&weight[(size_t)be * HID + k0 + bk + 4 * q];
            bS[bk + 4 * q + 0][be] = w.x;
            bS[bk + 4 * q + 1][be] = w.y;
            bS[bk + 4 * q + 2][be] = w.z;
            bS[bk + 4 * q + 3][be] = w.w;
        }
        __syncthreads();

        // ---- compute: per 4-k step: 8 ds_read_b128, 32 cvt, 64 v_fma_f64 ----
        #pragma unroll 4
        for (int c = 0; c < BK / 4; ++c) {
            float4 bf[4];   // bf[kk] = experts 4tx..4tx+3 at k = 4c+kk
            #pragma unroll
            for (int kk = 0; kk < 4; ++kk)
                bf[kk] = *(const float4*)&bS[4 * c + kk][tx * 4];
            double bd[4][4];
            #pragma unroll
            for (int kk = 0; kk < 4; ++kk) {
                bd[kk][0] = (double)bf[kk].x; bd[kk][1] = (double)bf[kk].y;
                bd[kk][2] = (double)bf[kk].z; bd[kk][3] = (double)bf[kk].w;
            }
            #pragma unroll
            for (int i = 0; i < 4; ++i) {
                const float4 af = *(const float4*)&aS[ty * 4 + i][4 * c];
                const double a0 = (double)af.x, a1 = (double)af.y;
                const double a2 = (double)af.z, a3 = (double)af.w;
                #pragma unroll
                for (int j = 0; j < 4; ++j) {
                    acc[i][j] = fma(a0, bd[0][j], acc[i][j]);
                    acc[i][j] = fma(a1, bd[1][j], acc[i][j]);
                    acc[i][j] = fma(a2, bd[2][j], acc[i][j]);
                    acc[i][j] = fma(a3, bd[3][j], acc[i][j]);
                }
            }
        }
        __syncthreads();
    }

    // ---- write logits to global (coalesced float4, rounded from f64) ----
    #pragma unroll
    for (int i = 0; i < 4; ++i) {
        const int tok = tok0 + ty * 4 + i;
        float4 v = make_float4((float)acc[i][0], (float)acc[i][1],
                               (float)acc[i][2], (float)acc[i][3]);
        *(float4*)&out_logits[(size_t)tok * NE + tx * 4] = v;
    }

    // ---- stash f64 logit tile in LDS (aliases staging bufs; K-loop ended
    //      with __syncthreads so all compute reads are done) ----
    #pragma unroll
    for (int i = 0; i < 4; ++i)
        #pragma unroll
        for (int j = 0; j < 4; ++j)
            lg[ty * 4 + i][tx * 4 + j] = acc[i][j];
    __syncthreads();

    // ---- per-token top-8 + renormalized softmax over the selected 8 ----
    // Full softmax denominator cancels under renorm: vals = exp(l-lmax)/sum_top8.
    const int wave = tid >> 6;   // 0..1
    const int lane = tid & 63;   // expert id for this lane

    for (int tt = wave; tt < TM; tt += 2) {
        double cur = lg[tt][lane];
        double first = 0.0, s = 0.0, myv = 0.0;
        int myi = 0;
        #pragma unroll
        for (int i = 0; i < TOPK; ++i) {
            double mv = cur;
            int    mi = lane;
            #pragma unroll
            for (int off = 32; off; off >>= 1) {
                const double ov = __shfl_xor(mv, off);
                const int    oi = __shfl_xor(mi, off);
                if (ov > mv || (ov == mv && oi < mi)) { mv = ov; mi = oi; }
            }
            if (i == 0) first = mv;
            const double e = exp(mv - first);
            s += e;
            if (lane == i)  { myv = e; myi = mi; }
            if (lane == mi) cur = -INFINITY;   // remove winner
        }
        if (lane < TOPK) {
            const int tok = tok0 + tt;
            out_vals[(size_t)tok * TOPK + lane] = (float)(myv / s);
            out_idxf[(size_t)tok * TOPK + lane] = (float)myi;
        }
    }
}

extern "C" void kernel_launch(void* const* d_in, const int* in_sizes, int n_in,
                              void* d_out, int out_size, void* d_ws, size_t ws_size,
                              hipStream_t stream) {
    const float* hidden = (const float*)d_in[0];   // [16384, 2048] f32
    const float* weight = (const float*)d_in[1];   // [64, 2048] f32

    float* out        = (float*)d_out;
    float* out_logits = out;                                    // 16384*64
    float* out_vals   = out + (size_t)T_TOKENS * NE;            // 16384*8
    float* out_idxf   = out + (size_t)T_TOKENS * NE
                            + (size_t)T_TOKENS * TOPK;          // 16384*8

    dim3 grid(T_TOKENS / TM);
    dim3 block(128);
    hipLaunchKernelGGL(router_kernel, grid, block, 0, stream,
                       hidden, weight, out_logits, out_vals, out_idxf);
}

// Round 6
// 419.738 us; speedup vs baseline: 1.1342x; 1.1342x over previous
//
#include <hip/hip_runtime.h>
#include <math.h>

// Problem constants
#define T_TOKENS 16384
#define HID      2048
#define NE       64     // experts
#define TOPK     8
// Tiling: 256 thr, thread tile 4 tok x 2 exp, TM=32 -> grid 512 = 2 blk/CU,
// 8 waves/CU (2/SIMD — the round-4 structure that hid latency; rounds 3/5
// showed 1 wave/SIMD is ~1.5-3x slower regardless of instruction counts).
#define TM       32
#define BK       64
#define ASTR     68     // A f32 row stride: 272 B (16B-aligned)
#define BSTR     68     // B' (K-major) f32 row stride: 272 B
// Gap threshold for exact-rescue: >= 2x worst-case f32 chunk-promoted logit
// error (~3e-5); typical error ~3e-7. Expected flagged tokens ~0.3/block.
#define EPS_GAP  1e-4

__global__ __launch_bounds__(256, 2) void router_kernel(
    const float* __restrict__ hidden,   // [T_TOKENS, HID]
    const float* __restrict__ weight,   // [NE, HID]
    float* __restrict__ out_logits,     // [T_TOKENS, NE]
    float* __restrict__ out_vals,       // [T_TOKENS, TOPK]
    float* __restrict__ out_idxf)       // [T_TOKENS, TOPK] (indices stored as float)
{
    // aS: [TM][ASTR] f32 row-major (tokens)   =  8704 B
    // bS: [BK][BSTR] f32 K-major (k rows)     = 17408 B   total 26112 B
    // Epilogue aliases lg[TM][65] f64 (16640 B) over the front.
    __shared__ __align__(16) char smem[(TM * ASTR + BK * BSTR) * 4];
    float (*aS)[ASTR] = reinterpret_cast<float(*)[ASTR]>(smem);
    float (*bS)[BSTR] = reinterpret_cast<float(*)[BSTR]>(smem + TM * ASTR * 4);
    double (*lg)[65]  = reinterpret_cast<double(*)[65]>(smem);

    const int tid  = threadIdx.x;
    const int tok0 = blockIdx.x * TM;

    // Compute map: 4 tokens x 2 experts per thread.
    // Wave: ty in {2w,2w+1} -> A float4 reads are 2-address broadcasts (cheap);
    // B float2 reads at [k][2*tx]: 32 unique addrs, contiguous 256 B, every
    // bank exactly twice (2-way aliasing is free per m136).
    const int ty = tid >> 5;   // 0..7  token group (4 tokens each)
    const int tx = tid & 31;   // 0..31 expert pair

    // f64 running accumulators, fed by per-chunk f32 partial sums (error
    // ~3e-7 typical); exact f64 rescue below fixes any ambiguous ranking.
    double acc[4][2];
    #pragma unroll
    for (int i = 0; i < 4; ++i) { acc[i][0] = 0.0; acc[i][1] = 0.0; }

    // Staging maps
    const int ar = tid >> 3;          // 0..31  A row (token)
    const int ac = (tid & 7) << 3;    // 0..56  A col start (8 f32/thread)
    const int be = tid >> 2;          // 0..63  B expert row
    const int bc = (tid & 3) << 4;    // 0..48  B col start (16 f32/thread)

    for (int k0 = 0; k0 < HID; k0 += BK) {
        // ---- stage A tile [TM][BK] f32 row-major (2 b128 writes/thread) ----
        *(float4*)&aS[ar][ac + 0] =
            *(const float4*)&hidden[(size_t)(tok0 + ar) * HID + k0 + ac + 0];
        *(float4*)&aS[ar][ac + 4] =
            *(const float4*)&hidden[(size_t)(tok0 + ar) * HID + k0 + ac + 4];
        // ---- stage B tile [NE][BK] f32 K-major (transpose in-flight) ----
        // Per scalar-write instr: bank = (16q+4c+be) mod 32, be=0..63 -> each
        // bank hit exactly twice (free); (tid&3)*16 k-offset is bank-neutral.
        #pragma unroll
        for (int q = 0; q < 4; ++q) {
            const float4 w = *(const float4*)&weight[(size_t)be * HID + k0 + bc + 4 * q];
            bS[bc + 4 * q + 0][be] = w.x;
            bS[bc + 4 * q + 1][be] = w.y;
            bS[bc + 4 * q + 2][be] = w.z;
            bS[bc + 4 * q + 3][be] = w.w;
        }
        __syncthreads();

        // ---- f32 compute for this chunk: 8 outputs x 64 k ----
        float ca[4][2];
        #pragma unroll
        for (int i = 0; i < 4; ++i) { ca[i][0] = 0.f; ca[i][1] = 0.f; }

        #pragma unroll 4
        for (int c = 0; c < BK / 4; ++c) {
            float2 b[4];   // b[kk] = experts {2tx,2tx+1} at k = 4c+kk
            #pragma unroll
            for (int kk = 0; kk < 4; ++kk)
                b[kk] = *(const float2*)&bS[4 * c + kk][2 * tx];
            #pragma unroll
            for (int i = 0; i < 4; ++i) {
                const float4 a = *(const float4*)&aS[ty * 4 + i][4 * c];
                ca[i][0] = fmaf(a.x, b[0].x, ca[i][0]);
                ca[i][0] = fmaf(a.y, b[1].x, ca[i][0]);
                ca[i][0] = fmaf(a.z, b[2].x, ca[i][0]);
                ca[i][0] = fmaf(a.w, b[3].x, ca[i][0]);
                ca[i][1] = fmaf(a.x, b[0].y, ca[i][1]);
                ca[i][1] = fmaf(a.y, b[1].y, ca[i][1]);
                ca[i][1] = fmaf(a.z, b[2].y, ca[i][1]);
                ca[i][1] = fmaf(a.w, b[3].y, ca[i][1]);
            }
        }
        __syncthreads();

        // ---- promote chunk partials to f64 (once per 64 k) ----
        #pragma unroll
        for (int i = 0; i < 4; ++i) {
            acc[i][0] += (double)ca[i][0];
            acc[i][1] += (double)ca[i][1];
        }
    }

    // ---- write logits to global (coalesced float2) ----
    #pragma unroll
    for (int i = 0; i < 4; ++i) {
        const int tok = tok0 + ty * 4 + i;
        float2 v = make_float2((float)acc[i][0], (float)acc[i][1]);
        *(float2*)&out_logits[(size_t)tok * NE + tx * 2] = v;
    }

    // ---- stash f64 logit tile in LDS (aliases staging bufs; K-loop ended
    //      with __syncthreads so all compute reads are done) ----
    #pragma unroll
    for (int i = 0; i < 4; ++i) {
        lg[ty * 4 + i][tx * 2 + 0] = acc[i][0];
        lg[ty * 4 + i][tx * 2 + 1] = acc[i][1];
    }
    __syncthreads();

    // ---- per-token top-8 + renorm softmax; exact f64 rescue if ambiguous ----
    // Renorm cancels the full softmax denom: vals = exp(l - lmax) / sum_top8.
    const int wave = tid >> 6;   // 0..3
    const int lane = tid & 63;   // expert id for this lane

    for (int tt = wave; tt < TM; tt += 4) {
        double cur = lg[tt][lane];
        double first = 0.0, s = 0.0, myv = 0.0;
        int myi = 0;
        double prev = 0.0, mingap = 1e30;
        // top-9 scan: 8 adjacent gaps among top-9 guard both the 8|9 selection
        // boundary and the ordering within the top-8.
        #pragma unroll
        for (int i = 0; i < TOPK + 1; ++i) {
            double mv = cur;
            int    mi = lane;
            #pragma unroll
            for (int off = 32; off; off >>= 1) {
                const double ov = __shfl_xor(mv, off);
                const int    oi = __shfl_xor(mi, off);
                if (ov > mv || (ov == mv && oi < mi)) { mv = ov; mi = oi; }
            }
            if (i == 0) first = mv;
            else        mingap = fmin(mingap, prev - mv);
            prev = mv;
            if (i < TOPK) {
                const double e = exp(mv - first);
                s += e;
                if (lane == i) { myv = e; myi = mi; }
            }
            if (lane == mi) cur = -INFINITY;   // remove winner
        }

        if (mingap < EPS_GAP) {   // wave-uniform branch; expected ~0.3/block
            // Exact f64 logits: lane = expert; weight rows are L2-hot.
            const float* __restrict__ hrow = hidden + (size_t)(tok0 + tt) * HID;
            const float* __restrict__ wrow = weight + (size_t)lane * HID;
            double d = 0.0;
            #pragma unroll 4
            for (int k = 0; k < HID; k += 4) {
                const float4 h = *(const float4*)&hrow[k];
                const float4 w = *(const float4*)&wrow[k];
                d = fma((double)h.x, (double)w.x, d);
                d = fma((double)h.y, (double)w.y, d);
                d = fma((double)h.z, (double)w.z, d);
                d = fma((double)h.w, (double)w.w, d);
            }
            cur = d; first = 0.0; s = 0.0; myv = 0.0; myi = 0;
            #pragma unroll
            for (int i = 0; i < TOPK; ++i) {
                double mv = cur;
                int    mi = lane;
                #pragma unroll
                for (int off = 32; off; off >>= 1) {
                    const double ov = __shfl_xor(mv, off);
                    const int    oi = __shfl_xor(mi, off);
                    if (ov > mv || (ov == mv && oi < mi)) { mv = ov; mi = oi; }
                }
                if (i == 0) first = mv;
                const double e = exp(mv - first);
                s += e;
                if (lane == i)  { myv = e; myi = mi; }
                if (lane == mi) cur = -INFINITY;
            }
        }

        if (lane < TOPK) {
            const int tok = tok0 + tt;
            out_vals[(size_t)tok * TOPK + lane] = (float)(myv / s);
            out_idxf[(size_t)tok * TOPK + lane] = (float)myi;
        }
    }
}

extern "C" void kernel_launch(void* const* d_in, const int* in_sizes, int n_in,
                              void* d_out, int out_size, void* d_ws, size_t ws_size,
                              hipStream_t stream) {
    const float* hidden = (const float*)d_in[0];   // [16384, 2048] f32
    const float* weight = (const float*)d_in[1];   // [64, 2048] f32

    float* out        = (float*)d_out;
    float* out_logits = out;                                    // 16384*64
    float* out_vals   = out + (size_t)T_TOKENS * NE;            // 16384*8
    float* out_idxf   = out + (size_t)T_TOKENS * NE
                            + (size_t)T_TOKENS * TOPK;          // 16384*8

    dim3 grid(T_TOKENS / TM);
    dim3 block(256);
    hipLaunchKernelGGL(router_kernel, grid, block, 0, stream,
                       hidden, weight, out_logits, out_vals, out_idxf);
}